// Round 1
// baseline (2781.306 us; speedup 1.0000x reference)
//
#include <hip/hip_runtime.h>
#include <cstdint>
#include <cstddef>

#define EPSF 1e-8f

// ---------------- conv1: x[256,1,28,28] (*) w[256,1,9,9] + b, relu -> h[256,256,20,20]
__global__ __launch_bounds__(448) void conv1_kernel(
    const float* __restrict__ x, const float* __restrict__ cw,
    const float* __restrict__ cb, float* __restrict__ h)
{
  int b = blockIdx.x, t = threadIdx.x;
  __shared__ float xs[784];
  for (int i = t; i < 784; i += 448) xs[i] = x[(size_t)b * 784 + i];
  __syncthreads();
  if (t >= 400) return;
  int oy = t / 20, ox = t % 20;
  float p[81];
#pragma unroll
  for (int ky = 0; ky < 9; ++ky)
#pragma unroll
    for (int kx = 0; kx < 9; ++kx)
      p[ky * 9 + kx] = xs[(oy + ky) * 28 + ox + kx];
  for (int co = 0; co < 256; ++co) {
    float a = cb[co];
    const float* w = cw + co * 81;
#pragma unroll
    for (int i = 0; i < 81; ++i) a = fmaf(p[i], w[i], a);
    h[((size_t)b * 256 + co) * 400 + t] = fmaxf(a, 0.f);
  }
}

// ---------------- transpose caps1_w [256co][20736q] -> wT[20736q][256co]
__global__ __launch_bounds__(256) void transpose_w_kernel(
    const float* __restrict__ w, float* __restrict__ wT)
{
  __shared__ float tile[64][65];
  int q0 = blockIdx.x * 64, c0 = blockIdx.y * 64;
  int lr = threadIdx.x >> 6, lc = threadIdx.x & 63;
#pragma unroll
  for (int i = 0; i < 16; ++i) {
    int row = lr + 4 * i;
    tile[row][lc] = w[(size_t)(c0 + row) * 20736 + q0 + lc];
  }
  __syncthreads();
#pragma unroll
  for (int i = 0; i < 16; ++i) {
    int row = lr + 4 * i;
    wT[(size_t)(q0 + row) * 256 + c0 + lc] = tile[lc][row];
  }
}

// ---------------- caps1: h[256,256,20,20] (*) wT (stride2, 9x9) + bias -> u[256,1152,8] (pre-squash)
// block = image b, 512 threads: co = t&255, ys-half = t>>8
__global__ __launch_bounds__(512) void caps1_kernel(
    const float* __restrict__ h, const float* __restrict__ wT,
    const float* __restrict__ c1b, float* __restrict__ u)
{
  int b = blockIdx.x, t = threadIdx.x;
  int co = t & 255;
  int ysb = __builtin_amdgcn_readfirstlane((t >> 8) * 3);  // wave-uniform
  float acc[3][6];
#pragma unroll
  for (int i = 0; i < 3; ++i)
#pragma unroll
    for (int j = 0; j < 6; ++j) acc[i][j] = 0.f;
  const float* hb = h + (size_t)b * 256 * 400;
  for (int ci = 0; ci < 256; ++ci) {
    float wr[81];
    const float* wp = wT + (size_t)ci * 81 * 256 + co;
#pragma unroll
    for (int k = 0; k < 81; ++k) wr[k] = wp[(size_t)k * 256];
    const float* hc = hb + (size_t)ci * 400;
#pragma unroll
    for (int ky = 0; ky < 9; ++ky) {
#pragma unroll
      for (int ysl = 0; ysl < 3; ++ysl) {
        const float* hr = hc + (2 * (ysb + ysl) + ky) * 20;  // wave-uniform row -> scalar loads
#pragma unroll
        for (int kx = 0; kx < 9; ++kx) {
          float wv = wr[ky * 9 + kx];
#pragma unroll
          for (int xs = 0; xs < 6; ++xs)
            acc[ysl][xs] = fmaf(hr[2 * xs + kx], wv, acc[ysl][xs]);
        }
      }
    }
  }
  float bias = c1b[co];
  int caps = co >> 3, ch = co & 7;
#pragma unroll
  for (int ysl = 0; ysl < 3; ++ysl)
#pragma unroll
    for (int xs = 0; xs < 6; ++xs) {
      int n = (ysb + ysl) * 192 + caps * 6 + xs;
      u[((size_t)b * 1152 + n) * 8 + ch] = acc[ysl][xs] + bias;
    }
}

// ---------------- squash over last dim (8), in place. 294912 vectors.
__global__ __launch_bounds__(256) void squash_kernel(float* __restrict__ u)
{
  size_t idx = (size_t)blockIdx.x * 256 + threadIdx.x;  // < 294912
  float4 a = ((const float4*)u)[idx * 2];
  float4 c = ((const float4*)u)[idx * 2 + 1];
  float sq = a.x * a.x + a.y * a.y + a.z * a.z + a.w * a.w +
             c.x * c.x + c.y * c.y + c.z * c.z + c.w * c.w;
  float scale = sq / ((1.f + sq) * sqrtf(sq + EPSF));
  a.x *= scale; a.y *= scale; a.z *= scale; a.w *= scale;
  c.x *= scale; c.y *= scale; c.z *= scale; c.w *= scale;
  ((float4*)u)[idx * 2] = a;
  ((float4*)u)[idx * 2 + 1] = c;
}

// ---------------- dynamic routing, fully per-(c,b). grid (10,256), block 256.
// x_hat held in registers: thread t owns n = t + 256*j (j<5, n<1152)
__global__ __launch_bounds__(256) void routing_kernel(
    const float* __restrict__ u, const float* __restrict__ W2, float* __restrict__ vout)
{
  int c = blockIdx.x, b = blockIdx.y, t = threadIdx.x;
  int wid = t >> 6, lane = t & 63;
  float xh[5][16];
  float bn[5] = {0, 0, 0, 0, 0};
  bool valid[5];
  const float* ub = u + (size_t)b * 1152 * 8;
  const float* Wc = W2 + (size_t)c * 1152 * 128;
#pragma unroll
  for (int j = 0; j < 5; ++j) {
    int n = t + 256 * j;
    valid[j] = (n < 1152);
    if (valid[j]) {
      const float4 ua = ((const float4*)(ub + (size_t)n * 8))[0];
      const float4 uc = ((const float4*)(ub + (size_t)n * 8))[1];
      float uv[8] = {ua.x, ua.y, ua.z, ua.w, uc.x, uc.y, uc.z, uc.w};
      const float* wn = Wc + (size_t)n * 128;
#pragma unroll
      for (int o = 0; o < 16; ++o) {
        float s = 0.f;
#pragma unroll
        for (int i = 0; i < 8; ++i) s = fmaf(uv[i], wn[i * 16 + o], s);
        xh[j][o] = s;
      }
    } else {
#pragma unroll
      for (int o = 0; o < 16; ++o) xh[j][o] = 0.f;
    }
  }
  __shared__ float redm[4], redz[4], reds[64], sv[16];
  float scale = 0.f;
  for (int it = 0; it < 3; ++it) {
    // softmax over n of bn (uniform across o by construction)
    float m = -1e30f;
#pragma unroll
    for (int j = 0; j < 5; ++j) if (valid[j]) m = fmaxf(m, bn[j]);
    for (int d = 1; d < 64; d <<= 1) m = fmaxf(m, __shfl_xor(m, d));
    if (lane == 0) redm[wid] = m;
    __syncthreads();
    m = fmaxf(fmaxf(redm[0], redm[1]), fmaxf(redm[2], redm[3]));
    float e[5]; float z = 0.f;
#pragma unroll
    for (int j = 0; j < 5; ++j) { e[j] = valid[j] ? expf(bn[j] - m) : 0.f; z += e[j]; }
    for (int d = 1; d < 64; d <<= 1) z += __shfl_xor(z, d);
    if (lane == 0) redz[wid] = z;
    __syncthreads();
    z = redz[0] + redz[1] + redz[2] + redz[3];
    // s = sum_n c_n * xh_n  (factor 1/z at the end)
    float ps[16];
#pragma unroll
    for (int o = 0; o < 16; ++o) ps[o] = 0.f;
#pragma unroll
    for (int j = 0; j < 5; ++j)
#pragma unroll
      for (int o = 0; o < 16; ++o) ps[o] = fmaf(e[j], xh[j][o], ps[o]);
#pragma unroll
    for (int o = 0; o < 16; ++o) {
      float vv = ps[o];
      for (int d = 1; d < 64; d <<= 1) vv += __shfl_xor(vv, d);
      if (lane == 0) reds[wid * 16 + o] = vv;
    }
    __syncthreads();
    if (t < 16) sv[t] = (reds[t] + reds[16 + t] + reds[32 + t] + reds[48 + t]) / z;
    __syncthreads();
    float vsc[16]; float sq = 0.f;
#pragma unroll
    for (int o = 0; o < 16; ++o) { vsc[o] = sv[o]; sq += sv[o] * sv[o]; }
    scale = sq / ((1.f + sq) * sqrtf(sq + EPSF));
    if (it < 2) {
#pragma unroll
      for (int j = 0; j < 5; ++j) if (valid[j]) {
        float dot = 0.f;
#pragma unroll
        for (int o = 0; o < 16; ++o) dot = fmaf(xh[j][o], vsc[o] * scale, dot);
        bn[j] += dot;
      }
    }
  }
  if (t < 16) vout[((size_t)c * 256 + b) * 16 + t] = sv[t] * scale;
}

// ---------------- class scores, softmax, argmax(first-max), mask. grid 256 (b), block 256.
__global__ __launch_bounds__(256) void classify_kernel(
    const float* __restrict__ v, float* __restrict__ probs, float* __restrict__ masked)
{
  int b = blockIdx.x, t = threadIdx.x;
  __shared__ float sc[10], vv[160];
  int c = t >> 4, o = t & 15;
  float val = 0.f;
  if (t < 160) { val = v[((size_t)c * 256 + b) * 16 + o]; vv[t] = val; }
  float sq = val * val;
  sq += __shfl_xor(sq, 1); sq += __shfl_xor(sq, 2);
  sq += __shfl_xor(sq, 4); sq += __shfl_xor(sq, 8);
  if (t < 160 && o == 0) sc[c] = sqrtf(sq + EPSF);
  __syncthreads();
  float m = sc[0];
#pragma unroll
  for (int i = 1; i < 10; ++i) m = fmaxf(m, sc[i]);
  float ee[10]; float Z = 0.f;
#pragma unroll
  for (int i = 0; i < 10; ++i) { ee[i] = expf(sc[i] - m); Z += ee[i]; }
  float p[10];
#pragma unroll
  for (int i = 0; i < 10; ++i) p[i] = ee[i] / Z;
  int label = 0; float best = p[0];
#pragma unroll
  for (int i = 1; i < 10; ++i) if (p[i] > best) { best = p[i]; label = i; }
  if (t < 10) probs[(size_t)b * 10 + t] = p[t];
  if (t < 160) masked[(size_t)b * 160 + t] = (c == label) ? vv[t] : 0.f;
}

// ---------------- decoder GEMM: C[M=256,N] = act(A[M,K] @ W[K,N] + bias). ACT 0=relu 1=sigmoid
template <int ACT>
__global__ __launch_bounds__(256) void mlp_kernel(
    const float* __restrict__ A, const float* __restrict__ W,
    const float* __restrict__ bias, float* __restrict__ C, int N, int K)
{
  int j = blockIdx.x * 64 + (threadIdx.x & 63);
  int ty = threadIdx.x >> 6;
  int m0 = blockIdx.y * 16;
  __shared__ float As[16][33];
  float acc[4] = {0.f, 0.f, 0.f, 0.f};
  for (int k0 = 0; k0 < K; k0 += 32) {
    for (int e = threadIdx.x; e < 512; e += 256) {
      int r = e >> 5, kk = e & 31;
      As[r][kk] = A[(size_t)(m0 + r) * K + k0 + kk];
    }
    __syncthreads();
    if (j < N) {
      for (int kk = 0; kk < 32; ++kk) {
        float wv = W[(size_t)(k0 + kk) * N + j];
#pragma unroll
        for (int r = 0; r < 4; ++r) acc[r] = fmaf(As[ty + 4 * r][kk], wv, acc[r]);
      }
    }
    __syncthreads();
  }
  if (j < N) {
    float bv = bias[j];
#pragma unroll
    for (int r = 0; r < 4; ++r) {
      float xx = acc[r] + bv;
      if (ACT == 0) xx = fmaxf(xx, 0.f);
      else xx = 1.f / (1.f + expf(-xx));
      C[(size_t)(m0 + ty + 4 * r) * N + j] = xx;
    }
  }
}

extern "C" void kernel_launch(void* const* d_in, const int* in_sizes, int n_in,
                              void* d_out, int out_size, void* d_ws, size_t ws_size,
                              hipStream_t stream)
{
  const float* x   = (const float*)d_in[0];
  const float* cw  = (const float*)d_in[1];
  const float* cb  = (const float*)d_in[2];
  const float* c1w = (const float*)d_in[3];
  const float* c1b = (const float*)d_in[4];
  const float* c2w = (const float*)d_in[5];
  const float* w1  = (const float*)d_in[6];
  const float* b1  = (const float*)d_in[7];
  const float* w2  = (const float*)d_in[8];
  const float* b2  = (const float*)d_in[9];
  const float* w3  = (const float*)d_in[10];
  const float* b3  = (const float*)d_in[11];
  float* out = (float*)d_out;

  float* ws     = (float*)d_ws;
  float* h      = ws;                 // 256*256*400   = 26,214,400
  float* wT     = h + 26214400;       // 20736*256     =  5,308,416
  float* u      = wT + 5308416;       // 256*1152*8    =  2,359,296
  float* v      = u + 2359296;        // 10*256*16     =     40,960
  float* masked = v + 40960;          // 256*160       =     40,960
  float* a1     = masked + 40960;     // 256*512       =    131,072
  float* a2     = a1 + 131072;        // 256*1024      =    262,144

  hipLaunchKernelGGL(transpose_w_kernel, dim3(324, 4), dim3(256), 0, stream, c1w, wT);
  hipLaunchKernelGGL(conv1_kernel, dim3(256), dim3(448), 0, stream, x, cw, cb, h);
  hipLaunchKernelGGL(caps1_kernel, dim3(256), dim3(512), 0, stream, h, wT, c1b, u);
  hipLaunchKernelGGL(squash_kernel, dim3(1152), dim3(256), 0, stream, u);
  hipLaunchKernelGGL(routing_kernel, dim3(10, 256), dim3(256), 0, stream, u, c2w, v);
  hipLaunchKernelGGL(classify_kernel, dim3(256), dim3(256), 0, stream, v, out, masked);
  hipLaunchKernelGGL(mlp_kernel<0>, dim3(8, 16), dim3(256), 0, stream, masked, w1, b1, a1, 512, 160);
  hipLaunchKernelGGL(mlp_kernel<0>, dim3(16, 16), dim3(256), 0, stream, a1, w2, b2, a2, 1024, 512);
  hipLaunchKernelGGL(mlp_kernel<1>, dim3(13, 16), dim3(256), 0, stream, a2, w3, b3, out + 2560, 784, 1024);
}

// Round 2
// 1404.448 us; speedup vs baseline: 1.9804x; 1.9804x over previous
//
#include <hip/hip_runtime.h>
#include <cstdint>
#include <cstddef>

#define EPSF 1e-8f

typedef __attribute__((ext_vector_type(8))) short bf16x8;
typedef __attribute__((ext_vector_type(4))) float f32x4;
typedef unsigned short ushort_t;

static __device__ __forceinline__ ushort_t f2bf(float f) {
  unsigned u = __builtin_bit_cast(unsigned, f);
  unsigned r = (u + 0x7FFFu + ((u >> 16) & 1u)) >> 16;
  return (ushort_t)r;
}
static __device__ __forceinline__ float bf2f(ushort_t h) {
  return __builtin_bit_cast(float, (unsigned)h << 16);
}

// ---------------- conv1: x[256,1,28,28] (*) w[256,1,9,9]+b, relu -> h2[b][400][256ci] bf16 hi/lo
// grid (20 oy, 256 b), 256 threads = ci. x rows are wave-uniform -> SGPR operands.
__global__ __launch_bounds__(256) void conv1_kernel(
    const float* __restrict__ x, const float* __restrict__ cw,
    const float* __restrict__ cb, ushort_t* __restrict__ h2hi, ushort_t* __restrict__ h2lo)
{
  int oy = blockIdx.x, b = blockIdx.y, ci = threadIdx.x;
  float w[81];
#pragma unroll
  for (int i = 0; i < 81; ++i) w[i] = cw[ci * 81 + i];
  float bias = cb[ci];
  float acc[20];
#pragma unroll
  for (int ox = 0; ox < 20; ++ox) acc[ox] = bias;
  const float* xb = x + (size_t)b * 784;
  for (int ky = 0; ky < 9; ++ky) {
    const float* row = xb + (oy + ky) * 28;  // uniform address -> scalar loads
    float rv[28];
#pragma unroll
    for (int c = 0; c < 28; ++c) rv[c] = row[c];
#pragma unroll
    for (int kx = 0; kx < 9; ++kx) {
      float wv = w[ky * 9 + kx];
#pragma unroll
      for (int ox = 0; ox < 20; ++ox)
        acc[ox] = fmaf(rv[ox + kx], wv, acc[ox]);
    }
  }
#pragma unroll
  for (int ox = 0; ox < 20; ++ox) {
    float a = fmaxf(acc[ox], 0.f);
    ushort_t hi = f2bf(a);
    ushort_t lo = f2bf(a - bf2f(hi));
    size_t o = ((size_t)(b * 400 + oy * 20 + ox)) * 256 + ci;
    h2hi[o] = hi; h2lo[o] = lo;
  }
}

// ---------------- w2k prep: c1w[co][ci][81tap] fp32 -> w2k[co][tap*256+ci] bf16 hi/lo
__global__ __launch_bounds__(256) void w2k_prep_kernel(
    const float* __restrict__ c1w, ushort_t* __restrict__ w2khi, ushort_t* __restrict__ w2klo)
{
  int co = blockIdx.x, ci = threadIdx.x;
  const float* src = c1w + ((size_t)co * 256 + ci) * 81;
  size_t dst = (size_t)co * 20736 + ci;
  for (int tap = 0; tap < 81; ++tap) {
    float v = src[tap];
    ushort_t hi = f2bf(v);
    w2khi[dst + (size_t)tap * 256] = hi;
    w2klo[dst + (size_t)tap * 256] = f2bf(v - bf2f(hi));
  }
}

// ---------------- caps1 GEMM via MFMA, 3-term split-bf16.
// C[m=(pos,b)][n=co] = sum_k A[m][k] B[k][n], K=(tap,ci)=20736, K-split 4.
// grid 576 = 36 pos * 16 sub, sub = mt*8 + ks*2 + nt (bid%8 groups same (ks,nt) per XCD).
// 256 thr = 4 waves, each wave 64x64 (4x4 frags of 16x16x32).
__global__ __launch_bounds__(256, 2) void caps1_mfma_kernel(
    const ushort_t* __restrict__ h2hi, const ushort_t* __restrict__ h2lo,
    const ushort_t* __restrict__ w2khi, const ushort_t* __restrict__ w2klo,
    float* __restrict__ partial)
{
  int bid = blockIdx.x;
  int pos = bid >> 4, sub = bid & 15;
  int mt = sub >> 3, ks = (sub >> 1) & 3, nt = sub & 1;
  int ys = pos / 6, xs = pos % 6;
  int t = threadIdx.x;
  int wid = t >> 6, lane = t & 63;
  int wr = wid >> 1, wc = wid & 1;
  int lrow = lane & 15, g = lane >> 4;
  int b0 = mt * 128 + wr * 64;
  int n0 = nt * 128 + wc * 64;
  int cib = ks * 64;

  f32x4 acc[4][4];
#pragma unroll
  for (int i = 0; i < 4; ++i)
#pragma unroll
    for (int j = 0; j < 4; ++j) acc[i][j] = (f32x4){0.f, 0.f, 0.f, 0.f};

  const ushort_t* pA[4];
  const ushort_t* pB[4];
#pragma unroll
  for (int mf = 0; mf < 4; ++mf)
    pA[mf] = h2hi + ((size_t)(b0 + mf * 16 + lrow) * 400) * 256 + cib + 8 * g;
#pragma unroll
  for (int nf = 0; nf < 4; ++nf)
    pB[nf] = w2khi + (size_t)(n0 + nf * 16 + lrow) * 20736 + cib + 8 * g;
  ptrdiff_t dA = h2lo - h2hi;
  ptrdiff_t dB = w2klo - w2khi;

  for (int ky = 0; ky < 9; ++ky) {
    for (int kx = 0; kx < 9; ++kx) {
      int pix = (2 * ys + ky) * 20 + 2 * xs + kx;
      int tap = ky * 9 + kx;
      size_t offA = (size_t)pix * 256;
      size_t offB = (size_t)tap * 256;
      bf16x8 Ah[4][2], Al[4][2], Bh[4][2], Bl[4][2];
#pragma unroll
      for (int mf = 0; mf < 4; ++mf)
#pragma unroll
        for (int kb = 0; kb < 2; ++kb) {
          const ushort_t* q = pA[mf] + offA + kb * 32;
          Ah[mf][kb] = *(const bf16x8*)q;
          Al[mf][kb] = *(const bf16x8*)(q + dA);
        }
#pragma unroll
      for (int nf = 0; nf < 4; ++nf)
#pragma unroll
        for (int kb = 0; kb < 2; ++kb) {
          const ushort_t* q = pB[nf] + offB + kb * 32;
          Bh[nf][kb] = *(const bf16x8*)q;
          Bl[nf][kb] = *(const bf16x8*)(q + dB);
        }
#pragma unroll
      for (int kb = 0; kb < 2; ++kb)
#pragma unroll
        for (int mf = 0; mf < 4; ++mf)
#pragma unroll
          for (int nf = 0; nf < 4; ++nf) {
            acc[mf][nf] = __builtin_amdgcn_mfma_f32_16x16x32_bf16(Ah[mf][kb], Bh[nf][kb], acc[mf][nf], 0, 0, 0);
            acc[mf][nf] = __builtin_amdgcn_mfma_f32_16x16x32_bf16(Ah[mf][kb], Bl[nf][kb], acc[mf][nf], 0, 0, 0);
            acc[mf][nf] = __builtin_amdgcn_mfma_f32_16x16x32_bf16(Al[mf][kb], Bh[nf][kb], acc[mf][nf], 0, 0, 0);
          }
    }
  }
  // C/D layout: col = lane&15, row = g*4 + r  (m89-verified)
  float* pp = partial + (size_t)ks * 2359296;
#pragma unroll
  for (int mf = 0; mf < 4; ++mf) {
    int m = b0 + mf * 16 + g * 4;
#pragma unroll
    for (int nf = 0; nf < 4; ++nf) {
      int n = n0 + nf * 16 + lrow;
#pragma unroll
      for (int r = 0; r < 4; ++r)
        pp[((size_t)(pos * 256 + m + r)) * 256 + n] = acc[mf][nf][r];
    }
  }
}

// ---------------- combine K-splits + bias + squash -> u[b][1152][8]
__global__ __launch_bounds__(256) void combine_kernel(
    const float* __restrict__ partial, const float* __restrict__ c1b, float* __restrict__ u)
{
  int gidx = blockIdx.x * 256 + threadIdx.x;  // < 294912
  int caps = gidx & 31;
  int b = (gidx >> 5) & 255;
  int pos = gidx >> 13;
  int ys = pos / 6, xs = pos % 6;
  size_t base = ((size_t)pos * 256 + b) * 256 + caps * 8;
  f32x4 s0 = {0.f, 0.f, 0.f, 0.f}, s1 = {0.f, 0.f, 0.f, 0.f};
#pragma unroll
  for (int ksp = 0; ksp < 4; ++ksp) {
    const float* pp = partial + (size_t)ksp * 2359296 + base;
    s0 += *(const f32x4*)pp;
    s1 += *(const f32x4*)(pp + 4);
  }
  const float* bp = c1b + caps * 8;
#pragma unroll
  for (int i = 0; i < 4; ++i) { s0[i] += bp[i]; s1[i] += bp[4 + i]; }
  float sq = s0[0]*s0[0] + s0[1]*s0[1] + s0[2]*s0[2] + s0[3]*s0[3]
           + s1[0]*s1[0] + s1[1]*s1[1] + s1[2]*s1[2] + s1[3]*s1[3];
  float scale = sq / ((1.f + sq) * sqrtf(sq + EPSF));
  int nvec = ys * 192 + caps * 6 + xs;
  float* up = u + ((size_t)b * 1152 + nvec) * 8;
  f32x4 o0, o1;
#pragma unroll
  for (int i = 0; i < 4; ++i) { o0[i] = s0[i] * scale; o1[i] = s1[i] * scale; }
  *(f32x4*)up = o0;
  *(f32x4*)(up + 4) = o1;
}

// ---------------- dynamic routing, per-(c,b). grid (10,256), block 256.
__global__ __launch_bounds__(256) void routing_kernel(
    const float* __restrict__ u, const float* __restrict__ W2, float* __restrict__ vout)
{
  int c = blockIdx.x, b = blockIdx.y, t = threadIdx.x;
  int wid = t >> 6, lane = t & 63;
  float xh[5][16];
  float bn[5] = {0, 0, 0, 0, 0};
  bool valid[5];
  const float* ub = u + (size_t)b * 1152 * 8;
  const float* Wc = W2 + (size_t)c * 1152 * 128;
#pragma unroll
  for (int j = 0; j < 5; ++j) {
    int n = t + 256 * j;
    valid[j] = (n < 1152);
    if (valid[j]) {
      const float4 ua = ((const float4*)(ub + (size_t)n * 8))[0];
      const float4 uc = ((const float4*)(ub + (size_t)n * 8))[1];
      float uv[8] = {ua.x, ua.y, ua.z, ua.w, uc.x, uc.y, uc.z, uc.w};
      const float* wn = Wc + (size_t)n * 128;
#pragma unroll
      for (int o = 0; o < 16; ++o) {
        float s = 0.f;
#pragma unroll
        for (int i = 0; i < 8; ++i) s = fmaf(uv[i], wn[i * 16 + o], s);
        xh[j][o] = s;
      }
    } else {
#pragma unroll
      for (int o = 0; o < 16; ++o) xh[j][o] = 0.f;
    }
  }
  __shared__ float redm[4], redz[4], reds[64], sv[16];
  float scale = 0.f;
  for (int it = 0; it < 3; ++it) {
    float m = -1e30f;
#pragma unroll
    for (int j = 0; j < 5; ++j) if (valid[j]) m = fmaxf(m, bn[j]);
    for (int d = 1; d < 64; d <<= 1) m = fmaxf(m, __shfl_xor(m, d));
    if (lane == 0) redm[wid] = m;
    __syncthreads();
    m = fmaxf(fmaxf(redm[0], redm[1]), fmaxf(redm[2], redm[3]));
    float e[5]; float z = 0.f;
#pragma unroll
    for (int j = 0; j < 5; ++j) { e[j] = valid[j] ? expf(bn[j] - m) : 0.f; z += e[j]; }
    for (int d = 1; d < 64; d <<= 1) z += __shfl_xor(z, d);
    if (lane == 0) redz[wid] = z;
    __syncthreads();
    z = redz[0] + redz[1] + redz[2] + redz[3];
    float ps[16];
#pragma unroll
    for (int o = 0; o < 16; ++o) ps[o] = 0.f;
#pragma unroll
    for (int j = 0; j < 5; ++j)
#pragma unroll
      for (int o = 0; o < 16; ++o) ps[o] = fmaf(e[j], xh[j][o], ps[o]);
#pragma unroll
    for (int o = 0; o < 16; ++o) {
      float vv = ps[o];
      for (int d = 1; d < 64; d <<= 1) vv += __shfl_xor(vv, d);
      if (lane == 0) reds[wid * 16 + o] = vv;
    }
    __syncthreads();
    if (t < 16) sv[t] = (reds[t] + reds[16 + t] + reds[32 + t] + reds[48 + t]) / z;
    __syncthreads();
    float vsc[16]; float sq = 0.f;
#pragma unroll
    for (int o = 0; o < 16; ++o) { vsc[o] = sv[o]; sq += sv[o] * sv[o]; }
    scale = sq / ((1.f + sq) * sqrtf(sq + EPSF));
    if (it < 2) {
#pragma unroll
      for (int j = 0; j < 5; ++j) if (valid[j]) {
        float dot = 0.f;
#pragma unroll
        for (int o = 0; o < 16; ++o) dot = fmaf(xh[j][o], vsc[o] * scale, dot);
        bn[j] += dot;
      }
    }
    __syncthreads();
  }
  if (t < 16) vout[((size_t)c * 256 + b) * 16 + t] = sv[t] * scale;
}

// ---------------- class scores, softmax, argmax(first-max), mask. grid 256 (b).
__global__ __launch_bounds__(256) void classify_kernel(
    const float* __restrict__ v, float* __restrict__ probs, float* __restrict__ masked)
{
  int b = blockIdx.x, t = threadIdx.x;
  __shared__ float sc[10], vv[160];
  int c = t >> 4, o = t & 15;
  float val = 0.f;
  if (t < 160) { val = v[((size_t)c * 256 + b) * 16 + o]; vv[t] = val; }
  float sq = val * val;
  sq += __shfl_xor(sq, 1); sq += __shfl_xor(sq, 2);
  sq += __shfl_xor(sq, 4); sq += __shfl_xor(sq, 8);
  if (t < 160 && o == 0) sc[c] = sqrtf(sq + EPSF);
  __syncthreads();
  float m = sc[0];
#pragma unroll
  for (int i = 1; i < 10; ++i) m = fmaxf(m, sc[i]);
  float ee[10]; float Z = 0.f;
#pragma unroll
  for (int i = 0; i < 10; ++i) { ee[i] = expf(sc[i] - m); Z += ee[i]; }
  float p[10];
#pragma unroll
  for (int i = 0; i < 10; ++i) p[i] = ee[i] / Z;
  int label = 0; float best = p[0];
#pragma unroll
  for (int i = 1; i < 10; ++i) if (p[i] > best) { best = p[i]; label = i; }
  if (t < 10) probs[(size_t)b * 10 + t] = p[t];
  if (t < 160) masked[(size_t)b * 160 + t] = (c == label) ? vv[t] : 0.f;
}

// ---------------- decoder GEMM: C[M=256,N] = act(A[M,K] @ W[K,N] + bias). ACT 0=relu 1=sigmoid
template <int ACT>
__global__ __launch_bounds__(256) void mlp_kernel(
    const float* __restrict__ A, const float* __restrict__ W,
    const float* __restrict__ bias, float* __restrict__ C, int N, int K)
{
  int j = blockIdx.x * 64 + (threadIdx.x & 63);
  int ty = threadIdx.x >> 6;
  int m0 = blockIdx.y * 16;
  __shared__ float As[16][33];
  float acc[4] = {0.f, 0.f, 0.f, 0.f};
  for (int k0 = 0; k0 < K; k0 += 32) {
    for (int e = threadIdx.x; e < 512; e += 256) {
      int r = e >> 5, kk = e & 31;
      As[r][kk] = A[(size_t)(m0 + r) * K + k0 + kk];
    }
    __syncthreads();
    if (j < N) {
      for (int kk = 0; kk < 32; ++kk) {
        float wv = W[(size_t)(k0 + kk) * N + j];
#pragma unroll
        for (int r = 0; r < 4; ++r) acc[r] = fmaf(As[ty + 4 * r][kk], wv, acc[r]);
      }
    }
    __syncthreads();
  }
  if (j < N) {
    float bv = bias[j];
#pragma unroll
    for (int r = 0; r < 4; ++r) {
      float xx = acc[r] + bv;
      if (ACT == 0) xx = fmaxf(xx, 0.f);
      else xx = 1.f / (1.f + expf(-xx));
      C[(size_t)(m0 + ty + 4 * r) * N + j] = xx;
    }
  }
}

extern "C" void kernel_launch(void* const* d_in, const int* in_sizes, int n_in,
                              void* d_out, int out_size, void* d_ws, size_t ws_size,
                              hipStream_t stream)
{
  const float* x   = (const float*)d_in[0];
  const float* cw  = (const float*)d_in[1];
  const float* cb  = (const float*)d_in[2];
  const float* c1w = (const float*)d_in[3];
  const float* c1b = (const float*)d_in[4];
  const float* c2w = (const float*)d_in[5];
  const float* w1  = (const float*)d_in[6];
  const float* b1  = (const float*)d_in[7];
  const float* w2  = (const float*)d_in[8];
  const float* b2  = (const float*)d_in[9];
  const float* w3  = (const float*)d_in[10];
  const float* b3  = (const float*)d_in[11];
  float* out = (float*)d_out;

  char* p = (char*)d_ws;
  ushort_t* h2hi  = (ushort_t*)p; p += (size_t)26214400 * 2;
  ushort_t* h2lo  = (ushort_t*)p; p += (size_t)26214400 * 2;
  ushort_t* w2khi = (ushort_t*)p; p += (size_t)5308416 * 2;
  ushort_t* w2klo = (ushort_t*)p; p += (size_t)5308416 * 2;
  float* partial  = (float*)p;    p += (size_t)4 * 2359296 * 4;
  float* u        = (float*)p;    p += (size_t)2359296 * 4;
  float* v        = (float*)p;    p += (size_t)40960 * 4;
  float* masked   = (float*)p;    p += (size_t)40960 * 4;
  float* a1       = (float*)p;    p += (size_t)131072 * 4;
  float* a2       = (float*)p;    p += (size_t)262144 * 4;

  hipLaunchKernelGGL(w2k_prep_kernel, dim3(256), dim3(256), 0, stream, c1w, w2khi, w2klo);
  hipLaunchKernelGGL(conv1_kernel, dim3(20, 256), dim3(256), 0, stream, x, cw, cb, h2hi, h2lo);
  hipLaunchKernelGGL(caps1_mfma_kernel, dim3(576), dim3(256), 0, stream, h2hi, h2lo, w2khi, w2klo, partial);
  hipLaunchKernelGGL(combine_kernel, dim3(1152), dim3(256), 0, stream, partial, c1b, u);
  hipLaunchKernelGGL(routing_kernel, dim3(10, 256), dim3(256), 0, stream, u, c2w, v);
  hipLaunchKernelGGL(classify_kernel, dim3(256), dim3(256), 0, stream, v, out, masked);
  hipLaunchKernelGGL(mlp_kernel<0>, dim3(8, 16), dim3(256), 0, stream, masked, w1, b1, a1, 512, 160);
  hipLaunchKernelGGL(mlp_kernel<0>, dim3(16, 16), dim3(256), 0, stream, a1, w2, b2, a2, 1024, 512);
  hipLaunchKernelGGL(mlp_kernel<1>, dim3(13, 16), dim3(256), 0, stream, a2, w3, b3, out + 2560, 784, 1024);
}

// Round 3
// 849.482 us; speedup vs baseline: 3.2741x; 1.6533x over previous
//
#include <hip/hip_runtime.h>
#include <cstdint>
#include <cstddef>

#define EPSF 1e-8f

typedef __attribute__((ext_vector_type(8))) short bf16x8;
typedef __attribute__((ext_vector_type(4))) float f32x4;
typedef unsigned short ushort_t;

static __device__ __forceinline__ ushort_t f2bf(float f) {
  unsigned u = __builtin_bit_cast(unsigned, f);
  unsigned r = (u + 0x7FFFu + ((u >> 16) & 1u)) >> 16;
  return (ushort_t)r;
}
static __device__ __forceinline__ float bf2f(ushort_t h) {
  return __builtin_bit_cast(float, (unsigned)h << 16);
}

// ---------------- conv1: x[256,1,28,28] (*) w[256,1,9,9]+b, relu -> h2[b][400][256ci] bf16 hi/lo
__global__ __launch_bounds__(256) void conv1_kernel(
    const float* __restrict__ x, const float* __restrict__ cw,
    const float* __restrict__ cb, ushort_t* __restrict__ h2hi, ushort_t* __restrict__ h2lo)
{
  int oy = blockIdx.x, b = blockIdx.y, ci = threadIdx.x;
  float w[81];
#pragma unroll
  for (int i = 0; i < 81; ++i) w[i] = cw[ci * 81 + i];
  float bias = cb[ci];
  float acc[20];
#pragma unroll
  for (int ox = 0; ox < 20; ++ox) acc[ox] = bias;
  const float* xb = x + (size_t)b * 784;
  for (int ky = 0; ky < 9; ++ky) {
    const float* row = xb + (oy + ky) * 28;  // uniform address -> scalar loads
    float rv[28];
#pragma unroll
    for (int c = 0; c < 28; ++c) rv[c] = row[c];
#pragma unroll
    for (int kx = 0; kx < 9; ++kx) {
      float wv = w[ky * 9 + kx];
#pragma unroll
      for (int ox = 0; ox < 20; ++ox)
        acc[ox] = fmaf(rv[ox + kx], wv, acc[ox]);
    }
  }
#pragma unroll
  for (int ox = 0; ox < 20; ++ox) {
    float a = fmaxf(acc[ox], 0.f);
    ushort_t hi = f2bf(a);
    ushort_t lo = f2bf(a - bf2f(hi));
    size_t o = ((size_t)(b * 400 + oy * 20 + ox)) * 256 + ci;
    h2hi[o] = hi; h2lo[o] = lo;
  }
}

// ---------------- w2k prep: c1w[co][ci][81tap] fp32 -> w2k[co][tap*256+ci] bf16 hi/lo
__global__ __launch_bounds__(256) void w2k_prep_kernel(
    const float* __restrict__ c1w, ushort_t* __restrict__ w2khi, ushort_t* __restrict__ w2klo)
{
  int co = blockIdx.x, ci = threadIdx.x;
  const float* src = c1w + ((size_t)co * 256 + ci) * 81;
  size_t dst = (size_t)co * 20736 + ci;
  for (int tap = 0; tap < 81; ++tap) {
    float v = src[tap];
    ushort_t hi = f2bf(v);
    w2khi[dst + (size_t)tap * 256] = hi;
    w2klo[dst + (size_t)tap * 256] = f2bf(v - bf2f(hi));
  }
}

// ---------------- caps1 GEMM via MFMA, 3-term split-bf16, LDS-staged (m97-style).
// C[m=(pos,b)][n=co], K=(tap,ci)=20736. Block tile 128x128, 4 waves 64x64.
// K per block: ci-slice of 64 (ks=0..3), loop 81 taps, BK=64.
// grid 576: bid = ((pos*2 + nt)*2 + mt)*4 + ks -> bid%8 = mt*4+ks per XCD.
__global__ __launch_bounds__(256, 2) void caps1_mfma_kernel(
    const ushort_t* __restrict__ h2hi, const ushort_t* __restrict__ h2lo,
    const ushort_t* __restrict__ w2khi, const ushort_t* __restrict__ w2klo,
    float* __restrict__ partial)
{
  int bid = blockIdx.x;
  int ks  = bid & 3;
  int mt  = (bid >> 2) & 1;
  int nt  = (bid >> 3) & 1;
  int pos = bid >> 4;                 // 0..35
  int ys = pos / 6, xs = pos % 6;
  int t = threadIdx.x;
  int wid = t >> 6, lane = t & 63;
  int wr = wid >> 1, wc = wid & 1;    // 2x2 waves, each 64x64
  int lrow = lane & 15, g = lane >> 4;

  int b0 = mt * 128;
  int n0 = nt * 128;
  int cib = ks * 64;

  // LDS tiles: [128 rows][64 ci] bf16, rows = 128B = 8 chunks of 16B,
  // chunk-swizzled: logical chunk c lives at slot c ^ (row&7).
  __shared__ ushort_t Ah[128 * 64];
  __shared__ ushort_t Al[128 * 64];
  __shared__ ushort_t Bh[128 * 64];
  __shared__ ushort_t Bl[128 * 64];

  f32x4 acc[4][4];
#pragma unroll
  for (int i = 0; i < 4; ++i)
#pragma unroll
    for (int j = 0; j < 4; ++j) acc[i][j] = (f32x4){0.f, 0.f, 0.f, 0.f};

  // staging map: per issue i: row = i*32 + (t>>3), slot = t&7, fetch chunk = slot ^ (row&7)
  int r_ = t >> 3;                    // 0..31
  int s_ = t & 7;
  int c_ = s_ ^ (r_ & 7);             // (i*32) % 8 == 0 so row&7 == r_&7
  size_t aRowOff[4], bRowOff[4];
#pragma unroll
  for (int i = 0; i < 4; ++i) {
    aRowOff[i] = ((size_t)(b0 + i * 32 + r_)) * 400;            // * pix later
    bRowOff[i] = (size_t)(n0 + i * 32 + r_) * 20736;
  }
  ptrdiff_t dA = h2lo - h2hi;
  ptrdiff_t dB = w2klo - w2khi;

  for (int tap = 0; tap < 81; ++tap) {
    int ky = tap / 9, kx = tap - ky * 9;
    int pix = (2 * ys + ky) * 20 + 2 * xs + kx;
    // ---- stage tile (16 x global_load_lds dwordx4)
#pragma unroll
    for (int i = 0; i < 4; ++i) {
      const ushort_t* ga = h2hi + (aRowOff[i] + pix) * 256 + cib + c_ * 8;
      const ushort_t* gb = w2khi + bRowOff[i] + (size_t)tap * 256 + cib + c_ * 8;
      int ldsbase = (i * 32 + wid * 8) * 64;   // element index, wave-uniform
      __builtin_amdgcn_global_load_lds(ga,      &Ah[ldsbase], 16, 0, 0);
      __builtin_amdgcn_global_load_lds(ga + dA, &Al[ldsbase], 16, 0, 0);
      __builtin_amdgcn_global_load_lds(gb,      &Bh[ldsbase], 16, 0, 0);
      __builtin_amdgcn_global_load_lds(gb + dB, &Bl[ldsbase], 16, 0, 0);
    }
    __syncthreads();   // drains vmcnt before barrier

    // ---- compute: 2 k-segments of 32, 4x4 frags, 3 MFMA each
#pragma unroll
    for (int kseg = 0; kseg < 2; ++kseg) {
      bf16x8 a_h[4], a_l[4], b_h[4], b_l[4];
#pragma unroll
      for (int mf = 0; mf < 4; ++mf) {
        int row = wr * 64 + mf * 16 + lrow;
        int off = row * 64 + ((kseg * 4 + g) ^ (row & 7)) * 8;
        a_h[mf] = *(const bf16x8*)&Ah[off];
        a_l[mf] = *(const bf16x8*)&Al[off];
      }
#pragma unroll
      for (int nf = 0; nf < 4; ++nf) {
        int row = wc * 64 + nf * 16 + lrow;
        int off = row * 64 + ((kseg * 4 + g) ^ (row & 7)) * 8;
        b_h[nf] = *(const bf16x8*)&Bh[off];
        b_l[nf] = *(const bf16x8*)&Bl[off];
      }
#pragma unroll
      for (int mf = 0; mf < 4; ++mf)
#pragma unroll
        for (int nf = 0; nf < 4; ++nf) {
          acc[mf][nf] = __builtin_amdgcn_mfma_f32_16x16x32_bf16(a_h[mf], b_h[nf], acc[mf][nf], 0, 0, 0);
          acc[mf][nf] = __builtin_amdgcn_mfma_f32_16x16x32_bf16(a_h[mf], b_l[nf], acc[mf][nf], 0, 0, 0);
          acc[mf][nf] = __builtin_amdgcn_mfma_f32_16x16x32_bf16(a_l[mf], b_h[nf], acc[mf][nf], 0, 0, 0);
        }
    }
    __syncthreads();   // protect LDS from next iter's staging
  }

  // C/D layout: col = lane&15 (n), row = g*4 + r (m)  [round-2 verified]
  float* pp = partial + (size_t)ks * 2359296;
#pragma unroll
  for (int mf = 0; mf < 4; ++mf) {
    int m = b0 + wr * 64 + mf * 16 + g * 4;
#pragma unroll
    for (int nf = 0; nf < 4; ++nf) {
      int n = n0 + wc * 64 + nf * 16 + lrow;
#pragma unroll
      for (int r = 0; r < 4; ++r)
        pp[((size_t)(pos * 256 + m + r)) * 256 + n] = acc[mf][nf][r];
    }
  }
}

// ---------------- combine K-splits + bias + squash -> u[b][1152][8]
__global__ __launch_bounds__(256) void combine_kernel(
    const float* __restrict__ partial, const float* __restrict__ c1b, float* __restrict__ u)
{
  int gidx = blockIdx.x * 256 + threadIdx.x;  // < 294912
  int caps = gidx & 31;
  int b = (gidx >> 5) & 255;
  int pos = gidx >> 13;
  int ys = pos / 6, xs = pos % 6;
  size_t base = ((size_t)pos * 256 + b) * 256 + caps * 8;
  f32x4 s0 = {0.f, 0.f, 0.f, 0.f}, s1 = {0.f, 0.f, 0.f, 0.f};
#pragma unroll
  for (int ksp = 0; ksp < 4; ++ksp) {
    const float* pp = partial + (size_t)ksp * 2359296 + base;
    s0 += *(const f32x4*)pp;
    s1 += *(const f32x4*)(pp + 4);
  }
  const float* bp = c1b + caps * 8;
#pragma unroll
  for (int i = 0; i < 4; ++i) { s0[i] += bp[i]; s1[i] += bp[4 + i]; }
  float sq = s0[0]*s0[0] + s0[1]*s0[1] + s0[2]*s0[2] + s0[3]*s0[3]
           + s1[0]*s1[0] + s1[1]*s1[1] + s1[2]*s1[2] + s1[3]*s1[3];
  float scale = sq / ((1.f + sq) * sqrtf(sq + EPSF));
  int nvec = ys * 192 + caps * 6 + xs;
  float* up = u + ((size_t)b * 1152 + nvec) * 8;
  f32x4 o0, o1;
#pragma unroll
  for (int i = 0; i < 4; ++i) { o0[i] = s0[i] * scale; o1[i] = s1[i] * scale; }
  *(f32x4*)up = o0;
  *(f32x4*)(up + 4) = o1;
}

// ---------------- dynamic routing, per-(c,b). grid (256 b, 10 c) for W2 L2 locality.
__global__ __launch_bounds__(256) void routing_kernel(
    const float* __restrict__ u, const float* __restrict__ W2, float* __restrict__ vout)
{
  int b = blockIdx.x, c = blockIdx.y, t = threadIdx.x;
  int wid = t >> 6, lane = t & 63;
  float xh[5][16];
  float bn[5] = {0, 0, 0, 0, 0};
  bool valid[5];
  const float* ub = u + (size_t)b * 1152 * 8;
  const float* Wc = W2 + (size_t)c * 1152 * 128;
#pragma unroll
  for (int j = 0; j < 5; ++j) {
    int n = t + 256 * j;
    valid[j] = (n < 1152);
    if (valid[j]) {
      const float4 ua = ((const float4*)(ub + (size_t)n * 8))[0];
      const float4 uc = ((const float4*)(ub + (size_t)n * 8))[1];
      float uv[8] = {ua.x, ua.y, ua.z, ua.w, uc.x, uc.y, uc.z, uc.w};
      const float* wn = Wc + (size_t)n * 128;
#pragma unroll
      for (int o = 0; o < 16; ++o) {
        float s = 0.f;
#pragma unroll
        for (int i = 0; i < 8; ++i) s = fmaf(uv[i], wn[i * 16 + o], s);
        xh[j][o] = s;
      }
    } else {
#pragma unroll
      for (int o = 0; o < 16; ++o) xh[j][o] = 0.f;
    }
  }
  __shared__ float redm[4], redz[4], reds[64], sv[16];
  float scale = 0.f;
  for (int it = 0; it < 3; ++it) {
    float m = -1e30f;
#pragma unroll
    for (int j = 0; j < 5; ++j) if (valid[j]) m = fmaxf(m, bn[j]);
    for (int d = 1; d < 64; d <<= 1) m = fmaxf(m, __shfl_xor(m, d));
    if (lane == 0) redm[wid] = m;
    __syncthreads();
    m = fmaxf(fmaxf(redm[0], redm[1]), fmaxf(redm[2], redm[3]));
    float e[5]; float z = 0.f;
#pragma unroll
    for (int j = 0; j < 5; ++j) { e[j] = valid[j] ? expf(bn[j] - m) : 0.f; z += e[j]; }
    for (int d = 1; d < 64; d <<= 1) z += __shfl_xor(z, d);
    if (lane == 0) redz[wid] = z;
    __syncthreads();
    z = redz[0] + redz[1] + redz[2] + redz[3];
    float ps[16];
#pragma unroll
    for (int o = 0; o < 16; ++o) ps[o] = 0.f;
#pragma unroll
    for (int j = 0; j < 5; ++j)
#pragma unroll
      for (int o = 0; o < 16; ++o) ps[o] = fmaf(e[j], xh[j][o], ps[o]);
#pragma unroll
    for (int o = 0; o < 16; ++o) {
      float vv = ps[o];
      for (int d = 1; d < 64; d <<= 1) vv += __shfl_xor(vv, d);
      if (lane == 0) reds[wid * 16 + o] = vv;
    }
    __syncthreads();
    if (t < 16) sv[t] = (reds[t] + reds[16 + t] + reds[32 + t] + reds[48 + t]) / z;
    __syncthreads();
    float vsc[16]; float sq = 0.f;
#pragma unroll
    for (int o = 0; o < 16; ++o) { vsc[o] = sv[o]; sq += sv[o] * sv[o]; }
    scale = sq / ((1.f + sq) * sqrtf(sq + EPSF));
    if (it < 2) {
#pragma unroll
      for (int j = 0; j < 5; ++j) if (valid[j]) {
        float dot = 0.f;
#pragma unroll
        for (int o = 0; o < 16; ++o) dot = fmaf(xh[j][o], vsc[o] * scale, dot);
        bn[j] += dot;
      }
    }
    __syncthreads();
  }
  if (t < 16) vout[((size_t)c * 256 + b) * 16 + t] = sv[t] * scale;
}

// ---------------- class scores, softmax, argmax(first-max), mask. grid 256 (b).
__global__ __launch_bounds__(256) void classify_kernel(
    const float* __restrict__ v, float* __restrict__ probs, float* __restrict__ masked)
{
  int b = blockIdx.x, t = threadIdx.x;
  __shared__ float sc[10], vv[160];
  int c = t >> 4, o = t & 15;
  float val = 0.f;
  if (t < 160) { val = v[((size_t)c * 256 + b) * 16 + o]; vv[t] = val; }
  float sq = val * val;
  sq += __shfl_xor(sq, 1); sq += __shfl_xor(sq, 2);
  sq += __shfl_xor(sq, 4); sq += __shfl_xor(sq, 8);
  if (t < 160 && o == 0) sc[c] = sqrtf(sq + EPSF);
  __syncthreads();
  float m = sc[0];
#pragma unroll
  for (int i = 1; i < 10; ++i) m = fmaxf(m, sc[i]);
  float ee[10]; float Z = 0.f;
#pragma unroll
  for (int i = 0; i < 10; ++i) { ee[i] = expf(sc[i] - m); Z += ee[i]; }
  float p[10];
#pragma unroll
  for (int i = 0; i < 10; ++i) p[i] = ee[i] / Z;
  int label = 0; float best = p[0];
#pragma unroll
  for (int i = 1; i < 10; ++i) if (p[i] > best) { best = p[i]; label = i; }
  if (t < 10) probs[(size_t)b * 10 + t] = p[t];
  if (t < 160) masked[(size_t)b * 160 + t] = (c == label) ? vv[t] : 0.f;
}

// ---------------- decoder GEMM: C[M=256,N] = act(A[M,K] @ W[K,N] + bias). ACT 0=relu 1=sigmoid
template <int ACT>
__global__ __launch_bounds__(256) void mlp_kernel(
    const float* __restrict__ A, const float* __restrict__ W,
    const float* __restrict__ bias, float* __restrict__ C, int N, int K)
{
  int j = blockIdx.x * 64 + (threadIdx.x & 63);
  int ty = threadIdx.x >> 6;
  int m0 = blockIdx.y * 16;
  __shared__ float As[16][33];
  float acc[4] = {0.f, 0.f, 0.f, 0.f};
  for (int k0 = 0; k0 < K; k0 += 32) {
    for (int e = threadIdx.x; e < 512; e += 256) {
      int r = e >> 5, kk = e & 31;
      As[r][kk] = A[(size_t)(m0 + r) * K + k0 + kk];
    }
    __syncthreads();
    if (j < N) {
      for (int kk = 0; kk < 32; ++kk) {
        float wv = W[(size_t)(k0 + kk) * N + j];
#pragma unroll
        for (int r = 0; r < 4; ++r) acc[r] = fmaf(As[ty + 4 * r][kk], wv, acc[r]);
      }
    }
    __syncthreads();
  }
  if (j < N) {
    float bv = bias[j];
#pragma unroll
    for (int r = 0; r < 4; ++r) {
      float xx = acc[r] + bv;
      if (ACT == 0) xx = fmaxf(xx, 0.f);
      else xx = 1.f / (1.f + expf(-xx));
      C[(size_t)(m0 + ty + 4 * r) * N + j] = xx;
    }
  }
}

extern "C" void kernel_launch(void* const* d_in, const int* in_sizes, int n_in,
                              void* d_out, int out_size, void* d_ws, size_t ws_size,
                              hipStream_t stream)
{
  const float* x   = (const float*)d_in[0];
  const float* cw  = (const float*)d_in[1];
  const float* cb  = (const float*)d_in[2];
  const float* c1w = (const float*)d_in[3];
  const float* c1b = (const float*)d_in[4];
  const float* c2w = (const float*)d_in[5];
  const float* w1  = (const float*)d_in[6];
  const float* b1  = (const float*)d_in[7];
  const float* w2  = (const float*)d_in[8];
  const float* b2  = (const float*)d_in[9];
  const float* w3  = (const float*)d_in[10];
  const float* b3  = (const float*)d_in[11];
  float* out = (float*)d_out;

  char* p = (char*)d_ws;
  ushort_t* h2hi  = (ushort_t*)p; p += (size_t)26214400 * 2;
  ushort_t* h2lo  = (ushort_t*)p; p += (size_t)26214400 * 2;
  ushort_t* w2khi = (ushort_t*)p; p += (size_t)5308416 * 2;
  ushort_t* w2klo = (ushort_t*)p; p += (size_t)5308416 * 2;
  float* partial  = (float*)p;    p += (size_t)4 * 2359296 * 4;
  float* u        = (float*)p;    p += (size_t)2359296 * 4;
  float* v        = (float*)p;    p += (size_t)40960 * 4;
  float* masked   = (float*)p;    p += (size_t)40960 * 4;
  float* a1       = (float*)p;    p += (size_t)131072 * 4;
  float* a2       = (float*)p;    p += (size_t)262144 * 4;

  hipLaunchKernelGGL(w2k_prep_kernel, dim3(256), dim3(256), 0, stream, c1w, w2khi, w2klo);
  hipLaunchKernelGGL(conv1_kernel, dim3(20, 256), dim3(256), 0, stream, x, cw, cb, h2hi, h2lo);
  hipLaunchKernelGGL(caps1_mfma_kernel, dim3(576), dim3(256), 0, stream, h2hi, h2lo, w2khi, w2klo, partial);
  hipLaunchKernelGGL(combine_kernel, dim3(1152), dim3(256), 0, stream, partial, c1b, u);
  hipLaunchKernelGGL(routing_kernel, dim3(256, 10), dim3(256), 0, stream, u, c2w, v);
  hipLaunchKernelGGL(classify_kernel, dim3(256), dim3(256), 0, stream, v, out, masked);
  hipLaunchKernelGGL(mlp_kernel<0>, dim3(8, 16), dim3(256), 0, stream, masked, w1, b1, a1, 512, 160);
  hipLaunchKernelGGL(mlp_kernel<0>, dim3(16, 16), dim3(256), 0, stream, a1, w2, b2, a2, 1024, 512);
  hipLaunchKernelGGL(mlp_kernel<1>, dim3(13, 16), dim3(256), 0, stream, a2, w3, b3, out + 2560, 784, 1024);
}